// Round 19
// baseline (96.827 us; speedup 1.0000x reference)
//
#include <hip/hip_runtime.h>
#include <hip/hip_bf16.h>

// Problem constants
#define BB 2
#define SS 2048
#define DD 1024
#define HH 16
#define MMR (BB*SS)   // 4096 rows
#define ND3 3072      // fused QKV width

typedef __hip_bfloat16 bf;
typedef __bf16 bf16x8 __attribute__((ext_vector_type(8)));
typedef float f32x4 __attribute__((ext_vector_type(4)));
typedef float f32x16 __attribute__((ext_vector_type(16)));

#define VMCNT(n) asm volatile("s_waitcnt vmcnt(" #n ")" ::: "memory")

__device__ __forceinline__ f32x4 mfma16(bf16x8 a, bf16x8 b, f32x4 c) {
    return __builtin_amdgcn_mfma_f32_16x16x32_bf16(a, b, c, 0, 0, 0);
}
__device__ __forceinline__ f32x16 mfma32(bf16x8 a, bf16x8 b, f32x16 c) {
    return __builtin_amdgcn_mfma_f32_32x32x16_bf16(a, b, c, 0, 0, 0);
}
__device__ __forceinline__ unsigned cvt_pk_bf16(float lo, float hi) {
    unsigned r;
    asm("v_cvt_pk_bf16_f32 %0, %1, %2" : "=v"(r) : "v"(lo), "v"(hi));
    return r;
}
// after: a = {a.lo31, b.lo31}, b = {a.hi31, b.hi31}
__device__ __forceinline__ void pl32swap(unsigned& a, unsigned& b) {
    asm("v_permlane32_swap_b32 %0, %1" : "+v"(a), "+v"(b));
}
// async global->LDS, 16B/lane; LDS dest = wave-uniform base + lane*16
__device__ __forceinline__ void glds16(const bf* g, bf* l) {
    __builtin_amdgcn_global_load_lds(
        (const __attribute__((address_space(1))) void*)g,
        (__attribute__((address_space(3))) void*)l,
        16, 0, 0);
}

// ---------------------------------------------------------------
// All f32->bf16 converts in ONE launch. blocks 0..4095: X (4M elems);
// blocks 4096..8191: Wq,Wk,Wv (into Wqkv) and Wo (into Wob), 1M each.
__global__ __launch_bounds__(256) void k_convert(const float* __restrict__ X,
                                                 const float* __restrict__ Wq,
                                                 const float* __restrict__ Wk,
                                                 const float* __restrict__ Wv,
                                                 const float* __restrict__ Wo,
                                                 bf* __restrict__ Xb,
                                                 bf* __restrict__ Wqkv,
                                                 bf* __restrict__ Wob) {
    const int bid = blockIdx.x;
    const float* src;
    bf* dst;
    int off;
    if (bid < 4096) {
        src = X; dst = Xb; off = bid;
    } else {
        const int r = (bid - 4096) >> 10;
        src = (r == 0) ? Wq : (r == 1) ? Wk : (r == 2) ? Wv : Wo;
        dst = (r < 3) ? (Wqkv + (size_t)r * 1048576) : Wob;
        off = (bid - 4096) & 1023;
    }
    const int j = (off * 256 + threadIdx.x) * 4;
    float4 v = *(const float4*)(src + j);
    bf tmp[4];
    tmp[0] = __float2bfloat16(v.x);
    tmp[1] = __float2bfloat16(v.y);
    tmp[2] = __float2bfloat16(v.z);
    tmp[3] = __float2bfloat16(v.w);
    *(uint2*)(dst + j) = *(const uint2*)tmp;
}

// ---------------------------------------------------------------
// QKV GEMM v4: 128x128 tile, **BK=64**, 8 waves. 2-buffer (64KB LDS),
// pair-unrolled compile-time buffers, running global source pointers.
// 16 K-steps (half the barrier/vmcnt chains of BK=32), 16 MFMA/wave/step.
// Tile pattern = attn's proven 64-row x 128B chunk staging: source
// pre-swizzle sblk=(lane&7)^srow, read seg^(row&7). Plain
// __launch_bounds__(512) (no min-waves: r15 spill lesson).
// Fused epilogue: cols<2048 -> per-head L2-norm*mask -> Qn/Kn [B*H,S,64];
// cols>=2048 -> transposed bf16 write to Vt [B*H,64,S]. K fixed = 1024.
__global__ __launch_bounds__(512) void k_gemm8(const bf* __restrict__ A,
                                               const bf* __restrict__ Bt,
                                               const int* __restrict__ masks,
                                               bf* __restrict__ Qn,
                                               bf* __restrict__ Kn,
                                               bf* __restrict__ Vt,
                                               int nx) {
    constexpr int K = 1024;
    constexpr int T = K >> 6;        // 16 K-steps of 64
    __shared__ __align__(16) bf Asm[2][128 * 64];   // 32KB
    __shared__ __align__(16) bf Bsm[2][128 * 64];   // 32KB
    const int tid = threadIdx.x;
    const int w = tid >> 6, lane = tid & 63, g = lane >> 4, rl = lane & 15;
    const int cpx = gridDim.x >> 3;
    const int swz = (blockIdx.x & 7) * cpx + (blockIdx.x >> 3);
    const int m0 = (swz / nx) * 128, n0 = (swz % nx) * 128;
    const int wr = (w >> 1) * 32, wc = (w & 1) * 64;
    // staging: chunk = 8 rows x 128B; wave w stages A,B chunks {2w, 2w+1}
    const int srow = lane >> 3;                // 0..7
    const int sblk = (lane & 7) ^ srow;        // pre-swizzled 16B slot

    f32x4 acc[2][4] = {};

    // running source pointers: +64 elems per K-step; chunk u=1 at +8 rows
    const bf* asr = A + (size_t)(m0 + w * 16 + srow) * K + sblk * 8;
    const bf* bsr = Bt + (size_t)(n0 + w * 16 + srow) * K + sblk * 8;
    bf* const adst = &Asm[0][w * 1024];        // chunks 2w (u=0), 2w+1 (+512)
    bf* const bdst = &Bsm[0][w * 1024];

    auto stageP = [&](int buf) {     // buf compile-time at every call site
        glds16(asr,           adst + buf * 8192);
        glds16(asr + 8 * K,   adst + buf * 8192 + 512);
        glds16(bsr,           bdst + buf * 8192);
        glds16(bsr + 8 * K,   bdst + buf * 8192 + 512);
        asr += 64; bsr += 64;
    };

    auto computeT = [&](const bf* Ab, const bf* Bb) {
        bf16x8 af[2][2], bfr[4][2];
#pragma unroll
        for (int m = 0; m < 2; ++m) {
            const int row = wr + m * 16 + rl;
#pragma unroll
            for (int ks = 0; ks < 2; ++ks)
                af[m][ks] = __builtin_bit_cast(bf16x8,
                    *(const int4*)&Ab[row * 64 + (((ks * 4 + g) ^ (row & 7)) << 3)]);
        }
#pragma unroll
        for (int n = 0; n < 4; ++n) {
            const int row = wc + n * 16 + rl;
#pragma unroll
            for (int ks = 0; ks < 2; ++ks)
                bfr[n][ks] = __builtin_bit_cast(bf16x8,
                    *(const int4*)&Bb[row * 64 + (((ks * 4 + g) ^ (row & 7)) << 3)]);
        }
        __builtin_amdgcn_s_setprio(1);
#pragma unroll
        for (int ks = 0; ks < 2; ++ks)
#pragma unroll
            for (int m = 0; m < 2; ++m)
#pragma unroll
                for (int n = 0; n < 4; ++n)
                    acc[m][n] = mfma16(af[m][ks], bfr[n][ks], acc[m][n]);
        __builtin_amdgcn_s_setprio(0);
    };

    stageP(0);                       // tile 0
    __syncthreads();
#pragma unroll 1
    for (int t = 0; t < T; t += 2) {
        stageP(1);                               // tile t+1 -> buf1
        computeT(&Asm[0][0], &Bsm[0][0]);        // tile t
        __syncthreads();
        if (t + 2 < T) stageP(0);                // tile t+2 -> buf0
        computeT(&Asm[1][0], &Bsm[1][0]);        // tile t+1
        __syncthreads();
    }

    const int ncol0 = n0 + wc;   // wave's 64-col base == one head slice
    if (ncol0 < 2048) {
        bf* dst = (ncol0 < 1024) ? Qn : Kn;
        const int h2 = (ncol0 >> 6) & 15;
#pragma unroll
        for (int m = 0; m < 2; ++m) {
#pragma unroll
            for (int ri = 0; ri < 4; ++ri) {
                const int row = m0 + wr + m * 16 + g * 4 + ri;   // b*S+s
                float ss = 0.f;
#pragma unroll
                for (int n = 0; n < 4; ++n) ss += acc[m][n][ri] * acc[m][n][ri];
#pragma unroll
                for (int d = 1; d < 16; d <<= 1) ss += __shfl_xor(ss, d, 64);
                const float sc = rsqrtf(ss) * (masks[row] ? 1.0f : 0.0f);
                const int b = row >> 11, s = row & 2047;
                const size_t base = ((size_t)(b * HH + h2) * SS + s) * 64;
#pragma unroll
                for (int n = 0; n < 4; ++n)
                    dst[base + n * 16 + rl] = __float2bfloat16(acc[m][n][ri] * sc);
            }
        }
    } else {
        // fused V transpose: Vt[(b*H+h)*64 + d][s], packed 4-bf16 writes
        const int h2 = (ncol0 - 2048) >> 6;
        const int b = (m0 + wr) >> 11;
        const int sb = ((m0 + wr) & 2047) + g * 4;
#pragma unroll
        for (int m = 0; m < 2; ++m)
#pragma unroll
            for (int n = 0; n < 4; ++n) {
                const int d = n * 16 + rl;
                bf t4[4];
#pragma unroll
                for (int ri = 0; ri < 4; ++ri) t4[ri] = __float2bfloat16(acc[m][n][ri]);
                *(uint2*)&Vt[((size_t)(b * HH + h2) * 64 + d) * SS + sb + m * 16] =
                    *(uint2*)t4;
            }
    }
}

// ---------------------------------------------------------------
// Out-proj GEMM v2 (r18-proven): 64x128 tile, BK=32, 4 waves; unroll-x3
// compile-time mod-3 buffers, running global source pointers. K=N=1024.
__global__ __launch_bounds__(256) void k_gemm(const bf* __restrict__ A,
                                              const bf* __restrict__ Bt,
                                              float* __restrict__ Cf,
                                              int nx) {
    constexpr int BM = 64, BN = 128;
    constexpr int K = 1024, N = 1024;
    constexpr int T = K >> 5;        // 32 K-steps
    __shared__ __align__(16) bf Asm[3][BM * 32];
    __shared__ __align__(16) bf Bsm[3][BN * 32];
    const int tid = threadIdx.x;
    const int w = tid >> 6, lane = tid & 63, g = lane >> 4, rl = lane & 15;
    const int cpx = gridDim.x >> 3;
    const int swz = (blockIdx.x & 7) * cpx + (blockIdx.x >> 3);
    const int m0 = (swz / nx) * BM, n0 = (swz % nx) * BN;
    const int wr = (w >> 1) * 32, wc = (w & 1) * 64;
    const int lrow = lane >> 2, lseg = lane & 3;
    const int xseg = lseg ^ ((lrow >> 1) & 3);

    f32x4 acc[2][4] = {};

    const bf* asr = A + (size_t)(m0 + w * 16 + lrow) * K + xseg * 8;
    const bf* bsr = Bt + (size_t)(n0 + w * 16 + lrow) * K + xseg * 8;
    bf* const adst = &Asm[0][w * 512];
    bf* const bdst = &Bsm[0][w * 512];

    auto stageP = [&](int buf) {     // buf compile-time at every call site
        glds16(asr, adst + buf * 2048);
        glds16(bsr, bdst + buf * 4096);
        glds16(bsr + 64 * K, bdst + buf * 4096 + 2048);
        asr += 32; bsr += 32;
    };

    auto computeT = [&](const bf* Ab, const bf* Bb) {
        bf16x8 af[2], bfr[4];
#pragma unroll
        for (int m = 0; m < 2; ++m) {
            const int row = wr + m * 16 + rl;
            af[m] = __builtin_bit_cast(bf16x8,
                *(const int4*)&Ab[row * 32 + (g ^ ((row >> 1) & 3)) * 8]);
        }
#pragma unroll
        for (int n = 0; n < 4; ++n) {
            const int row = wc + n * 16 + rl;
            bfr[n] = __builtin_bit_cast(bf16x8,
                *(const int4*)&Bb[row * 32 + (g ^ ((row >> 1) & 3)) * 8]);
        }
        __builtin_amdgcn_s_setprio(1);
#pragma unroll
        for (int m = 0; m < 2; ++m)
#pragma unroll
            for (int n = 0; n < 4; ++n)
                acc[m][n] = mfma16(af[m], bfr[n], acc[m][n]);
        __builtin_amdgcn_s_setprio(0);
    };

    auto step = [&](auto CURc, auto NXTc, int t) {
        constexpr int CUR = decltype(CURc)::value;
        constexpr int NXT = decltype(NXTc)::value;
        __builtin_amdgcn_sched_barrier(0);
        if (t < T - 1) { VMCNT(3); } else { VMCNT(0); }
        __builtin_amdgcn_s_barrier();
        __builtin_amdgcn_sched_barrier(0);
        if (t + 2 < T) stageP(NXT);
        computeT(&Asm[CUR][0], &Bsm[CUR][0]);
    };
    using c0 = std::integral_constant<int, 0>;
    using c1 = std::integral_constant<int, 1>;
    using c2 = std::integral_constant<int, 2>;

    stageP(0);
    stageP(1);
#pragma unroll 1
    for (int t = 0; t < 30; t += 3) {
        step(c0{}, c2{}, t);
        step(c1{}, c0{}, t + 1);
        step(c2{}, c1{}, t + 2);
    }
    step(c0{}, c2{}, 30);
    step(c1{}, c0{}, 31);

#pragma unroll
    for (int m = 0; m < 2; ++m)
#pragma unroll
        for (int n = 0; n < 4; ++n)
#pragma unroll
            for (int ri = 0; ri < 4; ++ri)
                Cf[(size_t)(m0 + wr + m * 16 + g * 4 + ri) * N + n0 + wc + n * 16 + rl] =
                    acc[m][n][ri];
}

// ---------------------------------------------------------------
// Attention v8 (r17/r18-proven): r14's per-wave body at 8 waves (512 thr),
// q-tile 128 = 4 q-halves x 2 k-parities; 2 glds16/tile/wave; pair-unrolled
// compile-time buffers + running global pointers; in-register P via cvt_pk +
// permlane32_swap; kp-partials summed via one-time LDS reduce.
__global__ __launch_bounds__(512) void k_attn(const bf* __restrict__ Qn,  // [B*H,S,64]
                                              const bf* __restrict__ Kn,  // [B*H,S,64]
                                              const bf* __restrict__ Vt,  // [B*H,64,S]
                                              bf* __restrict__ Ctx) {     // [B*S, D]
    __shared__ __align__(16) bf smem[16384];      // 32KB: K[2][4096] | V[2][4096]
    bf* const Ksm0 = smem;
    bf* const Vsm0 = smem + 8192;

    const int idx = blockIdx.x;           // 512 blocks
    const int qt = 15 - (idx >> 5);       // 0..15 (128-row q-tiles), largest-first
    const int by = idx & 31;              // b*H + h
    const int b = by >> 4, h = by & 15;
    const int tid = threadIdx.x;
    const int w = tid >> 6, lane = tid & 63;
    const int l31 = lane & 31, hl = lane >> 5;
    const int qh = w >> 1;                // 0..3: q rows qt*128 + qh*32 ..+32
    const int kp = w & 1;                 // k-parity: subtile kb = t*64+kp*32
    const int qw = qt * 128 + qh * 32;
    const int qg = qw + l31;

    const bf* Qp = Qn + (size_t)by * SS * 64;
    const bf* Kp = Kn + (size_t)by * SS * 64;
    const bf* Vp = Vt + (size_t)by * 64 * SS;

    // hoisted Q (B-operand): col=q=l31, d = st*16 + hl*8 + 0..7
    bf16x8 aqs[4];
#pragma unroll
    for (int st = 0; st < 4; ++st)
        aqs[st] = __builtin_bit_cast(bf16x8,
            *(const int4*)(Qp + (size_t)(qw + l31) * 64 + st * 16 + hl * 8));

    // staging: 16 chunks (8 K + 8 V) over 8 waves; pre-swizzled source slot
    const int srow = lane >> 3;
    const int sblk = (lane & 7) ^ srow;

    // running source pointers: tile t adds 4096 (K) / 64 (V)
    const bf* ksr = Kp + (size_t)(w * 8 + srow) * 64 + sblk * 8;
    const bf* vsr = Vp + (size_t)(w * 8 + srow) * SS + sblk * 8;
    bf* const kdst = Ksm0 + w * 512;
    bf* const vdst = Vsm0 + w * 512;

    auto stageP = [&](int buf) {          // buf compile-time at call sites
        glds16(ksr, kdst + buf * 4096);
        glds16(vsr, vdst + buf * 4096);
        ksr += 4096; vsr += 64;
    };

    f32x16 accd[2] = {};

    // per-tile compute (r14-verbatim body); Ks/Vs compile-time buffer bases
    auto doTile = [&](const bf* Ks, const bf* Vs, int t) {
        const int kb = t * 64 + kp * 32;
        if (kb > qw + 31) return;
        // ---- QK^T (swapped): D[row=k][col=q]
        f32x16 pc = {};
        const int r = kp * 32 + l31;
#pragma unroll
        for (int st = 0; st < 4; ++st) {
            bf16x8 ak = __builtin_bit_cast(bf16x8,
                *(const int4*)&Ks[r * 64 + (((2 * st + hl) ^ (r & 7)) << 3)]);
            pc = mfma32(ak, aqs[st], pc);
        }
        // ---- relu + causal (elementwise only near diagonal)
        const bool dg = (kb + 31 > qw);
        float pv[16];
#pragma unroll
        for (int m2 = 0; m2 < 16; ++m2) {
            float v = fmaxf(pc[m2], 0.0f);
            if (dg) {
                const int kg = kb + (m2 & 3) + 8 * (m2 >> 2) + 4 * hl;
                if (kg > qg) v = 0.0f;
            }
            pv[m2] = v;
        }
        // ---- pack to bf16 pairs + permlane swaps -> PV A-frags (no LDS)
        unsigned P[8];
#pragma unroll
        for (int m2 = 0; m2 < 8; ++m2) P[m2] = cvt_pk_bf16(pv[2 * m2], pv[2 * m2 + 1]);
        pl32swap(P[0], P[2]);
        pl32swap(P[1], P[3]);
        pl32swap(P[4], P[6]);
        pl32swap(P[5], P[7]);
        // ---- PV: D[row=q][col=d]
#pragma unroll
        for (int s = 0; s < 2; ++s) {
            uint4 pw = {P[4 * s + 0], P[4 * s + 1], P[4 * s + 2], P[4 * s + 3]};
            bf16x8 pa = __builtin_bit_cast(bf16x8, pw);
#pragma unroll
            for (int dt = 0; dt < 2; ++dt) {
                const int d = dt * 32 + l31;
                const int slot = kp * 4 + s * 2 + hl;
                bf16x8 bv = __builtin_bit_cast(bf16x8,
                    *(const int4*)&Vs[d * 64 + ((slot ^ (d & 7)) << 3)]);
                accd[dt] = mfma32(pa, bv, accd[dt]);
            }
        }
    };

    // prologue: tile 0 into buffer 0
    stageP(0);
    __syncthreads();

    // pair-unrolled loop: buffer0 = even tiles, buffer1 = odd tiles.
    // nt = 2*qt + 2 (always even -> no tail).
    const int nt = 2 * qt + 2;
    int t = 0;
    while (t + 1 < nt) {
        stageP(1);                               // tile t+1 -> buf1
        doTile(Ksm0, Vsm0, t);
        __syncthreads();
        if (t + 2 < nt) stageP(0);               // tile t+2 -> buf0
        doTile(Ksm0 + 4096, Vsm0 + 4096, t + 1);
        __syncthreads();
        t += 2;
    }

    // ---- cross-wave (k-parity) reduce via LDS (32KB: [4 qh][32 q][64 d]),
    // then kp==0 writes Ctx
    float* red = (float*)smem;
    if (kp == 1) {
#pragma unroll
        for (int dt = 0; dt < 2; ++dt)
#pragma unroll
            for (int m2 = 0; m2 < 16; ++m2)
                red[qh * 2048 + (dt * 16 + m2) * 64 + lane] = accd[dt][m2];
    }
    __syncthreads();
    if (kp == 0) {
#pragma unroll
        for (int dt = 0; dt < 2; ++dt)
#pragma unroll
            for (int m2 = 0; m2 < 16; ++m2) {
                const float v = accd[dt][m2] + red[qh * 2048 + (dt * 16 + m2) * 64 + lane];
                const int q = qw + (m2 & 3) + 8 * (m2 >> 2) + 4 * hl;
                const int d = dt * 32 + l31;
                Ctx[(size_t)(b * SS + q) * DD + h * 64 + d] = __float2bfloat16(v);
            }
    }
}

// ---------------------------------------------------------------
extern "C" void kernel_launch(void* const* d_in, const int* in_sizes, int n_in,
                              void* d_out, int out_size, void* d_ws, size_t ws_size,
                              hipStream_t stream) {
    const float* X  = (const float*)d_in[0];
    const int* masks = (const int*)d_in[1];
    const float* Wq = (const float*)d_in[2];
    const float* Wk = (const float*)d_in[3];
    const float* Wv = (const float*)d_in[4];
    const float* Wo = (const float*)d_in[5];
    float* out = (float*)d_out;
    char* ws = (char*)d_ws;

    const size_t MB = 1024 * 1024;
    bf* Xb   = (bf*)(ws);              // 8 MB  [B*S, D]
    bf* Wqkv = (bf*)(ws + 8  * MB);    // 6 MB  [3072, 1024]
    bf* Wob  = (bf*)(ws + 14 * MB);    // 2 MB
    bf* Qn   = (bf*)(ws + 16 * MB);    // 8 MB  [B*H, S, 64]
    bf* Kn   = (bf*)(ws + 24 * MB);
    bf* Vt   = (bf*)(ws + 32 * MB);    // 8 MB  [B*H, 64, S]
    bf* Ctx  = (bf*)(ws + 40 * MB);    // 8 MB  [B*S, D]

    // converts (one launch)
    k_convert<<<8192, 256, 0, stream>>>(X, Wq, Wk, Wv, Wo, Xb, Wqkv, Wob);

    // fused QKV projection + norm/mask epilogue + V-transpose
    // (128x128 tiles, BK=64, 2-buffer pair-unrolled, 768 blocks, 8 waves)
    k_gemm8<<<(ND3 / 128) * (MMR / 128), 512, 0, stream>>>(
        Xb, Wqkv, masks, Qn, Kn, Vt, ND3 / 128);

    // attention (8-wave q-tile-128, 512 blocks)
    k_attn<<<512, 512, 0, stream>>>(Qn, Kn, Vt, Ctx);

    // output projection (64x128 tiles -> 512 blocks, unrolled-x3)
    k_gemm<<<(DD / 128) * (MMR / 64), 256, 0, stream>>>(
        Ctx, Wob, out, DD / 128);
}

// Round 20
// 93.332 us; speedup vs baseline: 1.0374x; 1.0374x over previous
//
#include <hip/hip_runtime.h>
#include <hip/hip_bf16.h>

// Problem constants
#define BB 2
#define SS 2048
#define DD 1024
#define HH 16
#define MMR (BB*SS)   // 4096 rows
#define ND3 3072      // fused QKV width

typedef __hip_bfloat16 bf;
typedef __bf16 bf16x8 __attribute__((ext_vector_type(8)));
typedef float f32x4 __attribute__((ext_vector_type(4)));
typedef float f32x16 __attribute__((ext_vector_type(16)));

#define VMCNT(n) asm volatile("s_waitcnt vmcnt(" #n ")" ::: "memory")

__device__ __forceinline__ f32x4 mfma16(bf16x8 a, bf16x8 b, f32x4 c) {
    return __builtin_amdgcn_mfma_f32_16x16x32_bf16(a, b, c, 0, 0, 0);
}
__device__ __forceinline__ f32x16 mfma32(bf16x8 a, bf16x8 b, f32x16 c) {
    return __builtin_amdgcn_mfma_f32_32x32x16_bf16(a, b, c, 0, 0, 0);
}
__device__ __forceinline__ unsigned cvt_pk_bf16(float lo, float hi) {
    unsigned r;
    asm("v_cvt_pk_bf16_f32 %0, %1, %2" : "=v"(r) : "v"(lo), "v"(hi));
    return r;
}
// after: a = {a.lo31, b.lo31}, b = {a.hi31, b.hi31}
__device__ __forceinline__ void pl32swap(unsigned& a, unsigned& b) {
    asm("v_permlane32_swap_b32 %0, %1" : "+v"(a), "+v"(b));
}
// async global->LDS, 16B/lane; LDS dest = wave-uniform base + lane*16
__device__ __forceinline__ void glds16(const bf* g, bf* l) {
    __builtin_amdgcn_global_load_lds(
        (const __attribute__((address_space(1))) void*)g,
        (__attribute__((address_space(3))) void*)l,
        16, 0, 0);
}

// ---------------------------------------------------------------
// All f32->bf16 converts in ONE launch. blocks 0..4095: X (4M elems);
// blocks 4096..8191: Wq,Wk,Wv (into Wqkv) and Wo (into Wob), 1M each.
__global__ __launch_bounds__(256) void k_convert(const float* __restrict__ X,
                                                 const float* __restrict__ Wq,
                                                 const float* __restrict__ Wk,
                                                 const float* __restrict__ Wv,
                                                 const float* __restrict__ Wo,
                                                 bf* __restrict__ Xb,
                                                 bf* __restrict__ Wqkv,
                                                 bf* __restrict__ Wob) {
    const int bid = blockIdx.x;
    const float* src;
    bf* dst;
    int off;
    if (bid < 4096) {
        src = X; dst = Xb; off = bid;
    } else {
        const int r = (bid - 4096) >> 10;
        src = (r == 0) ? Wq : (r == 1) ? Wk : (r == 2) ? Wv : Wo;
        dst = (r < 3) ? (Wqkv + (size_t)r * 1048576) : Wob;
        off = (bid - 4096) & 1023;
    }
    const int j = (off * 256 + threadIdx.x) * 4;
    float4 v = *(const float4*)(src + j);
    bf tmp[4];
    tmp[0] = __float2bfloat16(v.x);
    tmp[1] = __float2bfloat16(v.y);
    tmp[2] = __float2bfloat16(v.z);
    tmp[3] = __float2bfloat16(v.w);
    *(uint2*)(dst + j) = *(const uint2*)tmp;
}

// ---------------------------------------------------------------
// QKV GEMM v3 (r16/r18-proven, ~37us): 3-buffer counted-vmcnt pipeline,
// K-loop unrolled x3 (compile-time buffer indices), running global source
// pointers. launch_bounds(512,6). Fused epilogue: per-head L2-norm*mask ->
// Qn/Kn; V cols -> transposed Vt. K fixed = 1024.
__global__ __launch_bounds__(512, 6) void k_gemm8(const bf* __restrict__ A,
                                                  const bf* __restrict__ Bt,
                                                  const int* __restrict__ masks,
                                                  bf* __restrict__ Qn,
                                                  bf* __restrict__ Kn,
                                                  bf* __restrict__ Vt,
                                                  int nx) {
    constexpr int K = 1024;
    constexpr int T = K >> 5;        // 32 K-steps
    __shared__ __align__(16) bf Asm[3][128 * 32];
    __shared__ __align__(16) bf Bsm[3][128 * 32];
    const int tid = threadIdx.x;
    const int w = tid >> 6, lane = tid & 63, g = lane >> 4, rl = lane & 15;
    const int cpx = gridDim.x >> 3;
    const int swz = (blockIdx.x & 7) * cpx + (blockIdx.x >> 3);
    const int m0 = (swz / nx) * 128, n0 = (swz % nx) * 128;
    const int wr = (w >> 1) * 32, wc = (w & 1) * 64;
    const int lrow = lane >> 2, lseg = lane & 3;
    const int xseg = lseg ^ ((lrow >> 1) & 3);   // pre-swizzled source seg

    f32x4 acc[2][4] = {};

    const bf* asr = A + (size_t)(m0 + w * 16 + lrow) * K + xseg * 8;
    const bf* bsr = Bt + (size_t)(n0 + w * 16 + lrow) * K + xseg * 8;
    bf* const adst = &Asm[0][w * 512];
    bf* const bdst = &Bsm[0][w * 512];

    auto stageP = [&](int buf) {     // buf is compile-time at every call site
        glds16(asr, adst + buf * 4096);
        glds16(bsr, bdst + buf * 4096);
        asr += 32; bsr += 32;
    };

    auto computeT = [&](const bf* Ab, const bf* Bb) {
        bf16x8 af[2], bfr[4];
#pragma unroll
        for (int m = 0; m < 2; ++m) {
            const int row = wr + m * 16 + rl;
            af[m] = __builtin_bit_cast(bf16x8,
                *(const int4*)&Ab[row * 32 + (g ^ ((row >> 1) & 3)) * 8]);
        }
#pragma unroll
        for (int n = 0; n < 4; ++n) {
            const int row = wc + n * 16 + rl;
            bfr[n] = __builtin_bit_cast(bf16x8,
                *(const int4*)&Bb[row * 32 + (g ^ ((row >> 1) & 3)) * 8]);
        }
        __builtin_amdgcn_s_setprio(1);
#pragma unroll
        for (int m = 0; m < 2; ++m)
#pragma unroll
            for (int n = 0; n < 4; ++n)
                acc[m][n] = mfma16(af[m], bfr[n], acc[m][n]);
        __builtin_amdgcn_s_setprio(0);
    };

    auto step = [&](auto CURc, auto NXTc, int t) {
        constexpr int CUR = decltype(CURc)::value;
        constexpr int NXT = decltype(NXTc)::value;
        __builtin_amdgcn_sched_barrier(0);
        if (t < T - 1) { VMCNT(2); } else { VMCNT(0); }
        __builtin_amdgcn_s_barrier();     // staged loads stay in flight
        __builtin_amdgcn_sched_barrier(0);
        if (t + 2 < T) stageP(NXT);
        computeT(&Asm[CUR][0], &Bsm[CUR][0]);
    };
    using c0 = std::integral_constant<int, 0>;
    using c1 = std::integral_constant<int, 1>;
    using c2 = std::integral_constant<int, 2>;

    stageP(0);
    stageP(1);
#pragma unroll 1
    for (int t = 0; t < 30; t += 3) {
        step(c0{}, c2{}, t);
        step(c1{}, c0{}, t + 1);
        step(c2{}, c1{}, t + 2);
    }
    step(c0{}, c2{}, 30);
    step(c1{}, c0{}, 31);

    const int ncol0 = n0 + wc;   // wave's 64-col base == one head slice
    if (ncol0 < 2048) {
        bf* dst = (ncol0 < 1024) ? Qn : Kn;
        const int h2 = (ncol0 >> 6) & 15;
#pragma unroll
        for (int m = 0; m < 2; ++m) {
#pragma unroll
            for (int ri = 0; ri < 4; ++ri) {
                const int row = m0 + wr + m * 16 + g * 4 + ri;   // b*S+s
                float ss = 0.f;
#pragma unroll
                for (int n = 0; n < 4; ++n) ss += acc[m][n][ri] * acc[m][n][ri];
#pragma unroll
                for (int d = 1; d < 16; d <<= 1) ss += __shfl_xor(ss, d, 64);
                const float sc = rsqrtf(ss) * (masks[row] ? 1.0f : 0.0f);
                const int b = row >> 11, s = row & 2047;
                const size_t base = ((size_t)(b * HH + h2) * SS + s) * 64;
#pragma unroll
                for (int n = 0; n < 4; ++n)
                    dst[base + n * 16 + rl] = __float2bfloat16(acc[m][n][ri] * sc);
            }
        }
    } else {
        // fused V transpose: Vt[(b*H+h)*64 + d][s], packed 4-bf16 writes
        const int h2 = (ncol0 - 2048) >> 6;
        const int b = (m0 + wr) >> 11;
        const int sb = ((m0 + wr) & 2047) + g * 4;
#pragma unroll
        for (int m = 0; m < 2; ++m)
#pragma unroll
            for (int n = 0; n < 4; ++n) {
                const int d = n * 16 + rl;
                bf t4[4];
#pragma unroll
                for (int ri = 0; ri < 4; ++ri) t4[ri] = __float2bfloat16(acc[m][n][ri]);
                *(uint2*)&Vt[((size_t)(b * HH + h2) * 64 + d) * SS + sb + m * 16] =
                    *(uint2*)t4;
            }
    }
}

// ---------------------------------------------------------------
// Out-proj GEMM v2 (r18-proven): 64x128 tile, BK=32, 4 waves; unroll-x3
// compile-time mod-3 buffers, running global source pointers. K=N=1024.
__global__ __launch_bounds__(256) void k_gemm(const bf* __restrict__ A,
                                              const bf* __restrict__ Bt,
                                              float* __restrict__ Cf,
                                              int nx) {
    constexpr int BM = 64, BN = 128;
    constexpr int K = 1024, N = 1024;
    constexpr int T = K >> 5;        // 32 K-steps
    __shared__ __align__(16) bf Asm[3][BM * 32];
    __shared__ __align__(16) bf Bsm[3][BN * 32];
    const int tid = threadIdx.x;
    const int w = tid >> 6, lane = tid & 63, g = lane >> 4, rl = lane & 15;
    const int cpx = gridDim.x >> 3;
    const int swz = (blockIdx.x & 7) * cpx + (blockIdx.x >> 3);
    const int m0 = (swz / nx) * BM, n0 = (swz % nx) * BN;
    const int wr = (w >> 1) * 32, wc = (w & 1) * 64;
    const int lrow = lane >> 2, lseg = lane & 3;
    const int xseg = lseg ^ ((lrow >> 1) & 3);

    f32x4 acc[2][4] = {};

    const bf* asr = A + (size_t)(m0 + w * 16 + lrow) * K + xseg * 8;
    const bf* bsr = Bt + (size_t)(n0 + w * 16 + lrow) * K + xseg * 8;
    bf* const adst = &Asm[0][w * 512];
    bf* const bdst = &Bsm[0][w * 512];

    auto stageP = [&](int buf) {     // buf compile-time at every call site
        glds16(asr, adst + buf * 2048);
        glds16(bsr, bdst + buf * 4096);
        glds16(bsr + 64 * K, bdst + buf * 4096 + 2048);
        asr += 32; bsr += 32;
    };

    auto computeT = [&](const bf* Ab, const bf* Bb) {
        bf16x8 af[2], bfr[4];
#pragma unroll
        for (int m = 0; m < 2; ++m) {
            const int row = wr + m * 16 + rl;
            af[m] = __builtin_bit_cast(bf16x8,
                *(const int4*)&Ab[row * 32 + (g ^ ((row >> 1) & 3)) * 8]);
        }
#pragma unroll
        for (int n = 0; n < 4; ++n) {
            const int row = wc + n * 16 + rl;
            bfr[n] = __builtin_bit_cast(bf16x8,
                *(const int4*)&Bb[row * 32 + (g ^ ((row >> 1) & 3)) * 8]);
        }
        __builtin_amdgcn_s_setprio(1);
#pragma unroll
        for (int m = 0; m < 2; ++m)
#pragma unroll
            for (int n = 0; n < 4; ++n)
                acc[m][n] = mfma16(af[m], bfr[n], acc[m][n]);
        __builtin_amdgcn_s_setprio(0);
    };

    auto step = [&](auto CURc, auto NXTc, int t) {
        constexpr int CUR = decltype(CURc)::value;
        constexpr int NXT = decltype(NXTc)::value;
        __builtin_amdgcn_sched_barrier(0);
        if (t < T - 1) { VMCNT(3); } else { VMCNT(0); }
        __builtin_amdgcn_s_barrier();
        __builtin_amdgcn_sched_barrier(0);
        if (t + 2 < T) stageP(NXT);
        computeT(&Asm[CUR][0], &Bsm[CUR][0]);
    };
    using c0 = std::integral_constant<int, 0>;
    using c1 = std::integral_constant<int, 1>;
    using c2 = std::integral_constant<int, 2>;

    stageP(0);
    stageP(1);
#pragma unroll 1
    for (int t = 0; t < 30; t += 3) {
        step(c0{}, c2{}, t);
        step(c1{}, c0{}, t + 1);
        step(c2{}, c1{}, t + 2);
    }
    step(c0{}, c2{}, 30);
    step(c1{}, c0{}, 31);

#pragma unroll
    for (int m = 0; m < 2; ++m)
#pragma unroll
        for (int n = 0; n < 4; ++n)
#pragma unroll
            for (int ri = 0; ri < 4; ++ri)
                Cf[(size_t)(m0 + wr + m * 16 + g * 4 + ri) * N + n0 + wc + n * 16 + rl] =
                    acc[m][n][ri];
}

// ---------------------------------------------------------------
// Attention v8 (r17/r18-proven): r14's per-wave body at 8 waves (512 thr),
// q-tile 128 = 4 q-halves x 2 k-parities; 2 glds16/tile/wave; pair-unrolled
// compile-time buffers + running global pointers; in-register P via cvt_pk +
// permlane32_swap; kp-partials summed via one-time LDS reduce.
__global__ __launch_bounds__(512) void k_attn(const bf* __restrict__ Qn,  // [B*H,S,64]
                                              const bf* __restrict__ Kn,  // [B*H,S,64]
                                              const bf* __restrict__ Vt,  // [B*H,64,S]
                                              bf* __restrict__ Ctx) {     // [B*S, D]
    __shared__ __align__(16) bf smem[16384];      // 32KB: K[2][4096] | V[2][4096]
    bf* const Ksm0 = smem;
    bf* const Vsm0 = smem + 8192;

    const int idx = blockIdx.x;           // 512 blocks
    const int qt = 15 - (idx >> 5);       // 0..15 (128-row q-tiles), largest-first
    const int by = idx & 31;              // b*H + h
    const int b = by >> 4, h = by & 15;
    const int tid = threadIdx.x;
    const int w = tid >> 6, lane = tid & 63;
    const int l31 = lane & 31, hl = lane >> 5;
    const int qh = w >> 1;                // 0..3: q rows qt*128 + qh*32 ..+32
    const int kp = w & 1;                 // k-parity: subtile kb = t*64+kp*32
    const int qw = qt * 128 + qh * 32;
    const int qg = qw + l31;

    const bf* Qp = Qn + (size_t)by * SS * 64;
    const bf* Kp = Kn + (size_t)by * SS * 64;
    const bf* Vp = Vt + (size_t)by * 64 * SS;

    // hoisted Q (B-operand): col=q=l31, d = st*16 + hl*8 + 0..7
    bf16x8 aqs[4];
#pragma unroll
    for (int st = 0; st < 4; ++st)
        aqs[st] = __builtin_bit_cast(bf16x8,
            *(const int4*)(Qp + (size_t)(qw + l31) * 64 + st * 16 + hl * 8));

    // staging: 16 chunks (8 K + 8 V) over 8 waves; pre-swizzled source slot
    const int srow = lane >> 3;
    const int sblk = (lane & 7) ^ srow;

    // running source pointers: tile t adds 4096 (K) / 64 (V)
    const bf* ksr = Kp + (size_t)(w * 8 + srow) * 64 + sblk * 8;
    const bf* vsr = Vp + (size_t)(w * 8 + srow) * SS + sblk * 8;
    bf* const kdst = Ksm0 + w * 512;
    bf* const vdst = Vsm0 + w * 512;

    auto stageP = [&](int buf) {          // buf compile-time at call sites
        glds16(ksr, kdst + buf * 4096);
        glds16(vsr, vdst + buf * 4096);
        ksr += 4096; vsr += 64;
    };

    f32x16 accd[2] = {};

    // per-tile compute (r14-verbatim body); Ks/Vs compile-time buffer bases
    auto doTile = [&](const bf* Ks, const bf* Vs, int t) {
        const int kb = t * 64 + kp * 32;
        if (kb > qw + 31) return;
        // ---- QK^T (swapped): D[row=k][col=q]
        f32x16 pc = {};
        const int r = kp * 32 + l31;
#pragma unroll
        for (int st = 0; st < 4; ++st) {
            bf16x8 ak = __builtin_bit_cast(bf16x8,
                *(const int4*)&Ks[r * 64 + (((2 * st + hl) ^ (r & 7)) << 3)]);
            pc = mfma32(ak, aqs[st], pc);
        }
        // ---- relu + causal (elementwise only near diagonal)
        const bool dg = (kb + 31 > qw);
        float pv[16];
#pragma unroll
        for (int m2 = 0; m2 < 16; ++m2) {
            float v = fmaxf(pc[m2], 0.0f);
            if (dg) {
                const int kg = kb + (m2 & 3) + 8 * (m2 >> 2) + 4 * hl;
                if (kg > qg) v = 0.0f;
            }
            pv[m2] = v;
        }
        // ---- pack to bf16 pairs + permlane swaps -> PV A-frags (no LDS)
        unsigned P[8];
#pragma unroll
        for (int m2 = 0; m2 < 8; ++m2) P[m2] = cvt_pk_bf16(pv[2 * m2], pv[2 * m2 + 1]);
        pl32swap(P[0], P[2]);
        pl32swap(P[1], P[3]);
        pl32swap(P[4], P[6]);
        pl32swap(P[5], P[7]);
        // ---- PV: D[row=q][col=d]
#pragma unroll
        for (int s = 0; s < 2; ++s) {
            uint4 pw = {P[4 * s + 0], P[4 * s + 1], P[4 * s + 2], P[4 * s + 3]};
            bf16x8 pa = __builtin_bit_cast(bf16x8, pw);
#pragma unroll
            for (int dt = 0; dt < 2; ++dt) {
                const int d = dt * 32 + l31;
                const int slot = kp * 4 + s * 2 + hl;
                bf16x8 bv = __builtin_bit_cast(bf16x8,
                    *(const int4*)&Vs[d * 64 + ((slot ^ (d & 7)) << 3)]);
                accd[dt] = mfma32(pa, bv, accd[dt]);
            }
        }
    };

    // prologue: tile 0 into buffer 0
    stageP(0);
    __syncthreads();

    // pair-unrolled loop: buffer0 = even tiles, buffer1 = odd tiles.
    // nt = 2*qt + 2 (always even -> no tail).
    const int nt = 2 * qt + 2;
    int t = 0;
    while (t + 1 < nt) {
        stageP(1);                               // tile t+1 -> buf1
        doTile(Ksm0, Vsm0, t);
        __syncthreads();
        if (t + 2 < nt) stageP(0);               // tile t+2 -> buf0
        doTile(Ksm0 + 4096, Vsm0 + 4096, t + 1);
        __syncthreads();
        t += 2;
    }

    // ---- cross-wave (k-parity) reduce via LDS (32KB: [4 qh][32 q][64 d]),
    // then kp==0 writes Ctx
    float* red = (float*)smem;
    if (kp == 1) {
#pragma unroll
        for (int dt = 0; dt < 2; ++dt)
#pragma unroll
            for (int m2 = 0; m2 < 16; ++m2)
                red[qh * 2048 + (dt * 16 + m2) * 64 + lane] = accd[dt][m2];
    }
    __syncthreads();
    if (kp == 0) {
#pragma unroll
        for (int dt = 0; dt < 2; ++dt)
#pragma unroll
            for (int m2 = 0; m2 < 16; ++m2) {
                const float v = accd[dt][m2] + red[qh * 2048 + (dt * 16 + m2) * 64 + lane];
                const int q = qw + (m2 & 3) + 8 * (m2 >> 2) + 4 * hl;
                const int d = dt * 32 + l31;
                Ctx[(size_t)(b * SS + q) * DD + h * 64 + d] = __float2bfloat16(v);
            }
    }
}

// ---------------------------------------------------------------
extern "C" void kernel_launch(void* const* d_in, const int* in_sizes, int n_in,
                              void* d_out, int out_size, void* d_ws, size_t ws_size,
                              hipStream_t stream) {
    const float* X  = (const float*)d_in[0];
    const int* masks = (const int*)d_in[1];
    const float* Wq = (const float*)d_in[2];
    const float* Wk = (const float*)d_in[3];
    const float* Wv = (const float*)d_in[4];
    const float* Wo = (const float*)d_in[5];
    float* out = (float*)d_out;
    char* ws = (char*)d_ws;

    const size_t MB = 1024 * 1024;
    bf* Xb   = (bf*)(ws);              // 8 MB  [B*S, D]
    bf* Wqkv = (bf*)(ws + 8  * MB);    // 6 MB  [3072, 1024]
    bf* Wob  = (bf*)(ws + 14 * MB);    // 2 MB
    bf* Qn   = (bf*)(ws + 16 * MB);    // 8 MB  [B*H, S, 64]
    bf* Kn   = (bf*)(ws + 24 * MB);
    bf* Vt   = (bf*)(ws + 32 * MB);    // 8 MB  [B*H, 64, S]
    bf* Ctx  = (bf*)(ws + 40 * MB);    // 8 MB  [B*S, D]

    // converts (one launch)
    k_convert<<<8192, 256, 0, stream>>>(X, Wq, Wk, Wv, Wo, Xb, Wqkv, Wob);

    // fused QKV projection + norm/mask epilogue + V-transpose
    // (128x128 tiles -> 768 blocks, 8 waves, 3-buffer unrolled-x3)
    k_gemm8<<<(ND3 / 128) * (MMR / 128), 512, 0, stream>>>(
        Xb, Wqkv, masks, Qn, Kn, Vt, ND3 / 128);

    // attention (8-wave q-tile-128, 512 blocks)
    k_attn<<<512, 512, 0, stream>>>(Qn, Kn, Vt, Ctx);

    // output projection (64x128 tiles -> 512 blocks, unrolled-x3)
    k_gemm<<<(DD / 128) * (MMR / 64), 256, 0, stream>>>(
        Ctx, Wob, out, DD / 128);
}